// Round 11
// baseline (2715.121 us; speedup 1.0000x reference)
//
#include <hip/hip_runtime.h>
#include <hip/hip_cooperative_groups.h>
#include <cstdint>
#include <cstddef>

// Problem constants (match the JAX reference)
#define MM 2
#define DD 128
#define RR 8
#define NN0 8192
#define LLV 32
#define KK 4096
#define NTHAX 1000
#define NTOT (NN0 + LLV*KK)     // 139264
#define NB 8                    // nodes per chunk
#define CHN8 520                // max chunks/level: ceil((4096 + 8*7)/8) = 519 -> 520
#define EBLK 2048               // eval blocks
#define TBLK 64                 // totals blocks

namespace cg = cooperative_groups;

// ---------------------------------------------------------------------------
// Preprocess: per level, counting-sort node indices by rule into NB-padded
// chunks so each level block-iteration handles exactly one rule.
// ---------------------------------------------------------------------------
__global__ void prep_kernel(const int* __restrict__ rule_ids,
                            int* __restrict__ chunk_nodes,   // [LLV][CHN8][NB]
                            int* __restrict__ chunk_rule,    // [LLV][CHN8]
                            int* __restrict__ nchunks)       // [LLV]
{
  const int l = blockIdx.x, t = threadIdx.x;
  __shared__ int cnt[RR], start[RR], fill[RR];
  if (t < RR){ cnt[t] = 0; fill[t] = 0; }
  __syncthreads();
  for (int k = t; k < KK; k += blockDim.x) atomicAdd(&cnt[rule_ids[l*KK + k]], 1);
  __syncthreads();
  if (t == 0){
    int s = 0;
    for (int r = 0; r < RR; ++r){
      start[r] = s;
      int pad = (cnt[r] + NB - 1)/NB*NB;
      for (int c = s/NB; c < (s+pad)/NB; ++c) chunk_rule[l*CHN8 + c] = r;
      s += pad;
    }
    nchunks[l] = s/NB;
  }
  __syncthreads();
  for (int i = t; i < CHN8*NB; i += blockDim.x) chunk_nodes[l*CHN8*NB + i] = -1;
  __syncthreads();
  for (int k = t; k < KK; k += blockDim.x){
    int r = rule_ids[l*KK + k];
    int p = start[r] + atomicAdd(&fill[r], 1);   // LDS atomics only
    chunk_nodes[l*CHN8*NB + p] = k;
  }
}

// ---------------------------------------------------------------------------
// Init nodes: store[i][m][d] = thax_table[m][thax[i]][d] * sigmoid(s*w + b)
// ---------------------------------------------------------------------------
__global__ void init_kernel(const int* __restrict__ thax_ids, const int* __restrict__ sine_ids,
                            const float* __restrict__ thax_table,
                            const float* __restrict__ sine_w, const float* __restrict__ sine_b,
                            float* __restrict__ store)
{
  int idx = blockIdx.x*blockDim.x + threadIdx.x;    // over NN0*MM*DD
  if (idx >= NN0*MM*DD) return;
  int i = idx >> 8;            // node
  int md = idx & 255;
  int m = md >> 7, d = md & 127;
  float emb = thax_table[((size_t)m*NTHAX + thax_ids[i])*DD + d];
  float s = (float)sine_ids[i];
  float z = s*sine_w[m*DD + d] + sine_b[m*DD + d];
  float sig = 1.f/(1.f + expf(-z));
  store[idx] = emb*sig;
}

// ---------------------------------------------------------------------------
// Totals: per-block partial sums of pos/neg (no atomics)
// ---------------------------------------------------------------------------
__global__ void totals_kernel(const float* __restrict__ pos, const float* __restrict__ neg,
                              float* __restrict__ pt)
{
  __shared__ float ts[4][2];
  const int t = threadIdx.x, lane = t & 63;
  float sp = 0.f, sn = 0.f;
  for (int n = blockIdx.x*blockDim.x + t; n < NTOT; n += gridDim.x*blockDim.x){
    sp += pos[n]; sn += neg[n];
  }
  #pragma unroll
  for (int s = 1; s < 64; s <<= 1){ sp += __shfl_xor(sp, s, 64); sn += __shfl_xor(sn, s, 64); }
  if (lane == 0){ ts[t>>6][0] = sp; ts[t>>6][1] = sn; }
  __syncthreads();
  if (t < 2) pt[t*TBLK + blockIdx.x] = ts[0][t] + ts[1][t] + ts[2][t] + ts[3][t];
}

// ---------------------------------------------------------------------------
// Shared per-pair body (round-9 proven structure), used by both the
// cooperative all-levels kernel and the per-level fallback kernel.
// ---------------------------------------------------------------------------
__device__ __forceinline__ void level_pair_body(
    float* __restrict__ store, const int* __restrict__ parents,
    const int* __restrict__ chunk_nodes, const int* __restrict__ chunk_rule,
    const float* __restrict__ W1, const float* __restrict__ b1,
    const float* __restrict__ W2, const float* __restrict__ b2,
    int level, int c, int m,
    float (*Xs)[2*DD], float (*RED)[NB][32][4], float (*Hlds)[DD],
    int* nd, int (*par)[2])
{
  const int t  = threadIdx.x;
  const int ej = t & 31;
  const int ni = (t >> 5) & 1;
  const int ks = t >> 6;
  const int e0 = ej * 4;
  const int r = chunk_rule[level*CHN8 + c];

  if (t < NB){
    int node = chunk_nodes[(level*CHN8 + c)*NB + t];
    nd[t] = node;
    const int* parL = parents + (size_t)level*KK*2;
    int p0 = 0, p1 = 0;
    if (node >= 0){ p0 = parL[node*2]; p1 = parL[node*2 + 1]; }
    par[t][0] = p0; par[t][1] = p1;
  }
  __syncthreads();

  // ---- Stage X: 512 float4s, 2 per thread, coalesced 512B runs ----
  #pragma unroll
  for (int q4 = 0; q4 < 2; ++q4){
    int q = q4*256 + t;
    int n = q >> 6, dq = q & 63;
    int p = par[n][dq >> 5];
    int col = (dq & 31) * 4;
    float4 v = *(const float4*)(store + (size_t)p*(MM*DD) + m*DD + col);
    *(float4*)&Xs[n][dq*4] = v;
  }
  __syncthreads();

  // ---------------- Layer 1: K rows [ks*64, ks*64+64) ----------------
  const float* W1p = W1 + (size_t)(m*RR + r)*(2*DD)*DD + (size_t)(ks*64)*DD;

  float acc[4][4];
  #pragma unroll
  for (int j = 0; j < 4; ++j){ acc[j][0]=0.f; acc[j][1]=0.f; acc[j][2]=0.f; acc[j][3]=0.f; }

  float4 wA[4], wB[4];
  #pragma unroll
  for (int i = 0; i < 4; ++i){
    wA[i] = *(const float4*)&W1p[(size_t)i*DD + e0];
    wB[i] = *(const float4*)&W1p[(size_t)(4 + i)*DD + e0];
  }
  #pragma unroll
  for (int kl = 0; kl < 64; kl += 8){
    {
      float4 xv[4];
      #pragma unroll
      for (int j = 0; j < 4; ++j) xv[j] = *(const float4*)&Xs[ni*4 + j][ks*64 + kl];
      #pragma unroll
      for (int i = 0; i < 4; ++i){
        float4 w4 = wA[i];
        #pragma unroll
        for (int j = 0; j < 4; ++j){
          float xs = (i==0) ? xv[j].x : (i==1) ? xv[j].y : (i==2) ? xv[j].z : xv[j].w;
          acc[j][0] = fmaf(xs, w4.x, acc[j][0]);
          acc[j][1] = fmaf(xs, w4.y, acc[j][1]);
          acc[j][2] = fmaf(xs, w4.z, acc[j][2]);
          acc[j][3] = fmaf(xs, w4.w, acc[j][3]);
        }
      }
      if (kl + 8 < 64){
        #pragma unroll
        for (int i = 0; i < 4; ++i) wA[i] = *(const float4*)&W1p[(size_t)(kl + 8 + i)*DD + e0];
      }
    }
    {
      float4 xv[4];
      #pragma unroll
      for (int j = 0; j < 4; ++j) xv[j] = *(const float4*)&Xs[ni*4 + j][ks*64 + kl + 4];
      #pragma unroll
      for (int i = 0; i < 4; ++i){
        float4 w4 = wB[i];
        #pragma unroll
        for (int j = 0; j < 4; ++j){
          float xs = (i==0) ? xv[j].x : (i==1) ? xv[j].y : (i==2) ? xv[j].z : xv[j].w;
          acc[j][0] = fmaf(xs, w4.x, acc[j][0]);
          acc[j][1] = fmaf(xs, w4.y, acc[j][1]);
          acc[j][2] = fmaf(xs, w4.z, acc[j][2]);
          acc[j][3] = fmaf(xs, w4.w, acc[j][3]);
        }
      }
      if (kl + 12 < 64){
        #pragma unroll
        for (int i = 0; i < 4; ++i) wB[i] = *(const float4*)&W1p[(size_t)(kl + 12 + i)*DD + e0];
      }
    }
  }

  #pragma unroll
  for (int j = 0; j < 4; ++j)
    *(float4*)&RED[ks][ni*4 + j][ej][0] = make_float4(acc[j][0], acc[j][1], acc[j][2], acc[j][3]);
  __syncthreads();

  // reduce 4 K-quarters, add bias, relu -> Hlds
  {
    const float* b1p = b1 + (m*RR + r)*DD;
    int n = t >> 5, e2 = t & 31;
    float4 a0 = *(const float4*)&RED[0][n][e2][0];
    float4 a1 = *(const float4*)&RED[1][n][e2][0];
    float4 a2 = *(const float4*)&RED[2][n][e2][0];
    float4 a3 = *(const float4*)&RED[3][n][e2][0];
    float4 bb = *(const float4*)&b1p[e2*4];
    float4 h;
    h.x = fmaxf(a0.x + a1.x + a2.x + a3.x + bb.x, 0.f);
    h.y = fmaxf(a0.y + a1.y + a2.y + a3.y + bb.y, 0.f);
    h.z = fmaxf(a0.z + a1.z + a2.z + a3.z + bb.z, 0.f);
    h.w = fmaxf(a0.w + a1.w + a2.w + a3.w + bb.w, 0.f);
    *(float4*)&Hlds[n][e2*4] = h;
  }
  __syncthreads();

  // ---------------- Layer 2: K rows [ks*32, ks*32+32) ----------------
  const float* W2p = W2 + (size_t)(m*RR + r)*DD*DD + (size_t)(ks*32)*DD;

  #pragma unroll
  for (int j = 0; j < 4; ++j){ acc[j][0]=0.f; acc[j][1]=0.f; acc[j][2]=0.f; acc[j][3]=0.f; }

  #pragma unroll
  for (int i = 0; i < 4; ++i){
    wA[i] = *(const float4*)&W2p[(size_t)i*DD + e0];
    wB[i] = *(const float4*)&W2p[(size_t)(4 + i)*DD + e0];
  }
  #pragma unroll
  for (int kl = 0; kl < 32; kl += 8){
    {
      float4 xv[4];
      #pragma unroll
      for (int j = 0; j < 4; ++j) xv[j] = *(const float4*)&Hlds[ni*4 + j][ks*32 + kl];
      #pragma unroll
      for (int i = 0; i < 4; ++i){
        float4 w4 = wA[i];
        #pragma unroll
        for (int j = 0; j < 4; ++j){
          float xs = (i==0) ? xv[j].x : (i==1) ? xv[j].y : (i==2) ? xv[j].z : xv[j].w;
          acc[j][0] = fmaf(xs, w4.x, acc[j][0]);
          acc[j][1] = fmaf(xs, w4.y, acc[j][1]);
          acc[j][2] = fmaf(xs, w4.z, acc[j][2]);
          acc[j][3] = fmaf(xs, w4.w, acc[j][3]);
        }
      }
      if (kl + 8 < 32){
        #pragma unroll
        for (int i = 0; i < 4; ++i) wA[i] = *(const float4*)&W2p[(size_t)(kl + 8 + i)*DD + e0];
      }
    }
    {
      float4 xv[4];
      #pragma unroll
      for (int j = 0; j < 4; ++j) xv[j] = *(const float4*)&Hlds[ni*4 + j][ks*32 + kl + 4];
      #pragma unroll
      for (int i = 0; i < 4; ++i){
        float4 w4 = wB[i];
        #pragma unroll
        for (int j = 0; j < 4; ++j){
          float xs = (i==0) ? xv[j].x : (i==1) ? xv[j].y : (i==2) ? xv[j].z : xv[j].w;
          acc[j][0] = fmaf(xs, w4.x, acc[j][0]);
          acc[j][1] = fmaf(xs, w4.y, acc[j][1]);
          acc[j][2] = fmaf(xs, w4.z, acc[j][2]);
          acc[j][3] = fmaf(xs, w4.w, acc[j][3]);
        }
      }
      if (kl + 12 < 32){
        #pragma unroll
        for (int i = 0; i < 4; ++i) wB[i] = *(const float4*)&W2p[(size_t)(kl + 12 + i)*DD + e0];
      }
    }
  }

  #pragma unroll
  for (int j = 0; j < 4; ++j)
    *(float4*)&RED[ks][ni*4 + j][ej][0] = make_float4(acc[j][0], acc[j][1], acc[j][2], acc[j][3]);
  __syncthreads();

  // reduce, add b2, write result rows (1 float4 per thread, coalesced)
  {
    const float* b2p = b2 + (m*RR + r)*DD;
    const size_t obase = (size_t)(NN0 + level*KK);
    int n = t >> 5, e2 = t & 31;
    int node = nd[n];
    if (node >= 0){
      float4 a0 = *(const float4*)&RED[0][n][e2][0];
      float4 a1 = *(const float4*)&RED[1][n][e2][0];
      float4 a2 = *(const float4*)&RED[2][n][e2][0];
      float4 a3 = *(const float4*)&RED[3][n][e2][0];
      float4 bb = *(const float4*)&b2p[e2*4];
      float4 o;
      o.x = a0.x + a1.x + a2.x + a3.x + bb.x;
      o.y = a0.y + a1.y + a2.y + a3.y + bb.y;
      o.z = a0.z + a1.z + a2.z + a3.z + bb.z;
      o.w = a0.w + a1.w + a2.w + a3.w + bb.w;
      *(float4*)&store[(obase + node)*(MM*DD) + m*DD + e2*4] = o;
    }
  }
}

// ---------------------------------------------------------------------------
// Cooperative all-levels kernel: grid-stride over pairs, grid.sync per level.
// ---------------------------------------------------------------------------
__global__ __launch_bounds__(256, 4) void levels_coop_kernel(
    float* __restrict__ store,
    const int* __restrict__ parents,
    const int* __restrict__ chunk_nodes,
    const int* __restrict__ chunk_rule,
    const int* __restrict__ nchunks,
    const float* __restrict__ W1, const float* __restrict__ b1,
    const float* __restrict__ W2, const float* __restrict__ b2)
{
  cg::grid_group grid = cg::this_grid();

  __shared__ float Xs[NB][2*DD];
  __shared__ float RED[4][NB][32][4];
  __shared__ float Hlds[NB][DD];
  __shared__ int nd[NB];
  __shared__ int par[NB][2];

  const int bid = blockIdx.x;
  const int gsz = gridDim.x;

  for (int level = 0; level < LLV; ++level){
    const int nch = nchunks[level];
    const int npairs = nch*2;
    for (int pair = bid; pair < npairs; pair += gsz){
      __syncthreads();                        // protect LDS reuse across pairs
      const int m = (pair >= nch) ? 1 : 0;
      const int c = pair - m*nch;
      level_pair_body(store, parents, chunk_nodes, chunk_rule, W1, b1, W2, b2,
                      level, c, m, Xs, RED, Hlds, nd, par);
    }
    grid.sync();                              // level barrier + device fence
  }
}

// ---------------------------------------------------------------------------
// Per-level fallback kernel (round-9 proven path).
// ---------------------------------------------------------------------------
__global__ __launch_bounds__(256, 4) void level_kernel(
    float* __restrict__ store,
    const int* __restrict__ parents,
    const int* __restrict__ chunk_nodes,
    const int* __restrict__ chunk_rule,
    const int* __restrict__ nchunks,
    const float* __restrict__ W1, const float* __restrict__ b1,
    const float* __restrict__ W2, const float* __restrict__ b2,
    int level)
{
  const int c = blockIdx.x;
  if (c >= nchunks[level]) return;
  const int m = blockIdx.y;

  __shared__ float Xs[NB][2*DD];
  __shared__ float RED[4][NB][32][4];
  __shared__ float Hlds[NB][DD];
  __shared__ int nd[NB];
  __shared__ int par[NB][2];

  level_pair_body(store, parents, chunk_nodes, chunk_rule, W1, b1, W2, b2,
                  level, c, m, Xs, RED, Hlds, nd, par);
}

// ---------------------------------------------------------------------------
// Eval: wave-per-node dot with w_eval (both m in one wave), stable BCE.
// Per-block partials (NO atomics): pe[c][blk], c = q*2 + m,
// q: 0=A (pw part), 1=B, 2=posOK, 3=negOK.  loss = pw*A + B in finish.
// ---------------------------------------------------------------------------
__global__ void eval_kernel(const float* __restrict__ store,
                            const float* __restrict__ pos_cnt, const float* __restrict__ neg_cnt,
                            const float* __restrict__ w_eval, const float* __restrict__ b_eval,
                            float* __restrict__ pe)
{
  __shared__ float part[4][2][4];      // [wave][m][q]
  const int t = threadIdx.x, lane = t & 63;
  const int gw = blockIdx.x*(blockDim.x >> 6) + (t >> 6);
  const int nw = gridDim.x*(blockDim.x >> 6);
  float4 wv = *(const float4*)&w_eval[4*lane];          // lanes 0-31 -> m=0, 32-63 -> m=1
  const int m = (lane >= 32) ? 1 : 0;
  const float be = b_eval[m];
  float A = 0.f, B = 0.f, pOK = 0.f, nOK = 0.f;
  for (int n = gw; n < NTOT; n += nw){
    float4 v = *(const float4*)&store[(size_t)n*(MM*DD) + 4*lane];
    float p = v.x*wv.x + v.y*wv.y + v.z*wv.z + v.w*wv.w;
    #pragma unroll
    for (int s = 1; s < 32; s <<= 1) p += __shfl_xor(p, s, 64);   // reduce within each m-half
    const float val = p + be;
    if ((lane & 31) == 0){
      const float pc = pos_cnt[n], nc = neg_cnt[n];
      const float cnt = pc + nc;
      if (cnt > 0.f){
        float gold = pc / fmaxf(cnt, 1.f);
        float e = log1pf(expf(-fabsf(val)));
        float sp_pos = e + fmaxf(val, 0.f);     // softplus(val)
        float sp_neg = e + fmaxf(-val, 0.f);    // softplus(-val)
        A += cnt * gold * sp_neg;
        B += cnt * (1.f - gold) * sp_pos;
      }
      pOK += (val >= 0.f) ? pc : 0.f;
      nOK += (val <  0.f) ? nc : 0.f;
    }
  }
  if ((lane & 31) == 0){
    int w = t >> 6;
    part[w][m][0] = A; part[w][m][1] = B; part[w][m][2] = pOK; part[w][m][3] = nOK;
  }
  __syncthreads();
  if (t < 8){
    int q = t >> 1, mm = t & 1;
    float s = part[0][mm][q] + part[1][mm][q] + part[2][mm][q] + part[3][mm][q];
    pe[t*EBLK + blockIdx.x] = s;
  }
}

// ---------------------------------------------------------------------------
// Finish: reduce totals + eval partials, compute pw, write 6 outputs.
// ---------------------------------------------------------------------------
__global__ void finish_kernel(const float* __restrict__ pt, const float* __restrict__ pe,
                              float* __restrict__ out)
{
  __shared__ float acc8[8];
  __shared__ float tt[2];
  const int t = threadIdx.x;             // 256
  if (t < 64){                           // totals: comp c = t>>5
    int c = t >> 5, l = t & 31;
    float s = pt[c*TBLK + l] + pt[c*TBLK + l + 32];
    #pragma unroll
    for (int d = 1; d < 32; d <<= 1) s += __shfl_xor(s, d, 64);
    if (l == 0) tt[c] = s;
  }
  {
    int comp = t >> 5, l = t & 31;
    float s = 0.f;
    for (int i = 0; i < EBLK/32; ++i) s += pe[comp*EBLK + i*32 + l];
    #pragma unroll
    for (int d = 1; d < 32; d <<= 1) s += __shfl_xor(s, d, 64);
    if (l == 0) acc8[comp] = s;
  }
  __syncthreads();
  if (t < 2){                            // m = t
    float tp = tt[0], tn = tt[1];
    float pw = (tp > 0.f) ? (tn / fmaxf(tp, 1.f)) : 1.f;   // POS_WEIGHT_EXTRA = 1
    out[t]     = pw*acc8[0 + t] + acc8[2 + t];
    out[2 + t] = acc8[4 + t];
    out[4 + t] = acc8[6 + t];
  }
}

// ---------------------------------------------------------------------------
extern "C" void kernel_launch(void* const* d_in, const int* in_sizes, int n_in,
                              void* d_out, int out_size, void* d_ws, size_t ws_size,
                              hipStream_t stream)
{
  const int*   thax_ids   = (const int*)d_in[0];
  const int*   sine_ids   = (const int*)d_in[1];
  const int*   parents    = (const int*)d_in[2];
  const int*   rule_ids   = (const int*)d_in[3];
  const float* pos_cnt    = (const float*)d_in[4];
  const float* neg_cnt    = (const float*)d_in[5];
  const float* thax_table = (const float*)d_in[6];
  const float* sine_w     = (const float*)d_in[7];
  const float* sine_b     = (const float*)d_in[8];
  const float* W1         = (const float*)d_in[9];
  const float* b1         = (const float*)d_in[10];
  const float* W2         = (const float*)d_in[11];
  const float* b2         = (const float*)d_in[12];
  const float* w_eval     = (const float*)d_in[13];
  const float* b_eval     = (const float*)d_in[14];

  char* ws = (char*)d_ws;
  float* store = (float*)ws;
  size_t off = (size_t)NTOT*MM*DD*sizeof(float);            // 142.6 MB
  int* chunk_nodes = (int*)(ws + off); off += (size_t)LLV*CHN8*NB*sizeof(int);
  int* chunk_rule  = (int*)(ws + off); off += (size_t)LLV*CHN8*sizeof(int);
  int* nchunks     = (int*)(ws + off); off += (size_t)LLV*sizeof(int);
  float* pt        = (float*)(ws + off); off += (size_t)2*TBLK*sizeof(float);
  float* pe        = (float*)(ws + off); off += (size_t)8*EBLK*sizeof(float);

  prep_kernel<<<LLV, 256, 0, stream>>>(rule_ids, chunk_nodes, chunk_rule, nchunks);
  init_kernel<<<(NN0*MM*DD + 255)/256, 256, 0, stream>>>(thax_ids, sine_ids, thax_table,
                                                         sine_w, sine_b, store);
  totals_kernel<<<TBLK, 256, 0, stream>>>(pos_cnt, neg_cnt, pt);

  // Cooperative all-levels launch, sized by the occupancy query; on ANY
  // failure fall back to the proven per-level loop (round-9 path).
  bool coop_ok = false;
  {
    int maxPerCU = 0;
    hipError_t qe = hipOccupancyMaxActiveBlocksPerMultiprocessor(
        &maxPerCU, levels_coop_kernel, 256, 0);
    if (qe == hipSuccess && maxPerCU > 0){
      int cgrid = maxPerCU * 256;
      if (cgrid > 1024) cgrid = 1024;
      void* args[] = { (void*)&store, (void*)&parents, (void*)&chunk_nodes,
                       (void*)&chunk_rule, (void*)&nchunks,
                       (void*)&W1, (void*)&b1, (void*)&W2, (void*)&b2 };
      hipError_t le = hipLaunchCooperativeKernel((void*)levels_coop_kernel,
                                                 dim3(cgrid), dim3(256), args, 0, stream);
      coop_ok = (le == hipSuccess);
    }
  }
  if (!coop_ok){
    for (int l = 0; l < LLV; ++l)
      level_kernel<<<dim3(CHN8, MM), 256, 0, stream>>>(store, parents, chunk_nodes, chunk_rule,
                                                       nchunks, W1, b1, W2, b2, l);
  }

  eval_kernel<<<EBLK, 256, 0, stream>>>(store, pos_cnt, neg_cnt, w_eval, b_eval, pe);
  finish_kernel<<<1, 256, 0, stream>>>(pt, pe, (float*)d_out);
}

// Round 12
// 352.256 us; speedup vs baseline: 7.7078x; 7.7078x over previous
//
#include <hip/hip_runtime.h>
#include <cstdint>
#include <cstddef>

// Problem constants (match the JAX reference)
#define MM 2
#define DD 128
#define RR 8
#define NN0 8192
#define LLV 32
#define KK 4096
#define NTHAX 1000
#define NTOT (NN0 + LLV*KK)     // 139264
#define NB 16                   // nodes per chunk (MFMA M-tile)
#define CHN16 264               // max chunks/level: ceil((4096 + 8*15)/16) = 264
#define EBLK 2048               // eval blocks
#define TBLK 64                 // totals blocks

typedef short bf16x8 __attribute__((ext_vector_type(8)));   // 8 bf16 (4 VGPRs)
typedef float f32x4  __attribute__((ext_vector_type(4)));

__device__ __forceinline__ unsigned short f2bf(float f){
  union { float f; uint32_t u; } x; x.f = f;
  uint32_t u = x.u + 0x7FFFu + ((x.u >> 16) & 1u);   // RNE
  return (unsigned short)(u >> 16);
}

// ---------------------------------------------------------------------------
// Preprocess: per level, counting-sort node indices by rule into NB-padded
// chunks so each level-kernel block handles exactly one rule.
// ---------------------------------------------------------------------------
__global__ void prep_kernel(const int* __restrict__ rule_ids,
                            int* __restrict__ chunk_nodes,   // [LLV][CHN16][NB]
                            int* __restrict__ chunk_rule,    // [LLV][CHN16]
                            int* __restrict__ nchunks)       // [LLV]
{
  const int l = blockIdx.x, t = threadIdx.x;
  __shared__ int cnt[RR], start[RR], fill[RR];
  if (t < RR){ cnt[t] = 0; fill[t] = 0; }
  __syncthreads();
  for (int k = t; k < KK; k += blockDim.x) atomicAdd(&cnt[rule_ids[l*KK + k]], 1);
  __syncthreads();
  if (t == 0){
    int s = 0;
    for (int r = 0; r < RR; ++r){
      start[r] = s;
      int pad = (cnt[r] + NB - 1)/NB*NB;
      for (int c = s/NB; c < (s+pad)/NB; ++c) chunk_rule[l*CHN16 + c] = r;
      s += pad;
    }
    nchunks[l] = s/NB;
  }
  __syncthreads();
  for (int i = t; i < CHN16*NB; i += blockDim.x) chunk_nodes[l*CHN16*NB + i] = -1;
  __syncthreads();
  for (int k = t; k < KK; k += blockDim.x){
    int r = rule_ids[l*KK + k];
    int p = start[r] + atomicAdd(&fill[r], 1);   // LDS atomics only
    chunk_nodes[l*CHN16*NB + p] = k;
  }
}

// ---------------------------------------------------------------------------
// Weight conversion fp32 -> bf16 in MFMA-B-fragment-native layout:
// Wt[(mr*(K/8) + kb)*DD*8 + e*8 + j] = bf16(W[(mr*K + kb*8+j)*DD + e])
// Lane's 8 k-values for a column are then 16B contiguous.
// ---------------------------------------------------------------------------
__global__ void convw_kernel(const float* __restrict__ W, unsigned short* __restrict__ Wt, int K)
{
  int idx = blockIdx.x*blockDim.x + threadIdx.x;   // over MM*RR*K*DD
  if (idx >= MM*RR*K*DD) return;
  int e = idx & 127;
  int k = (idx >> 7) % K;
  int mr = idx / (K*DD);
  float v = W[((size_t)mr*K + k)*DD + e];
  int kb = k >> 3, j = k & 7;
  Wt[((size_t)mr*(K >> 3) + kb)*DD*8 + e*8 + j] = f2bf(v);
}

// ---------------------------------------------------------------------------
// Init nodes: store[i][m][d] = thax_table[m][thax[i]][d] * sigmoid(s*w + b)
// ---------------------------------------------------------------------------
__global__ void init_kernel(const int* __restrict__ thax_ids, const int* __restrict__ sine_ids,
                            const float* __restrict__ thax_table,
                            const float* __restrict__ sine_w, const float* __restrict__ sine_b,
                            float* __restrict__ store)
{
  int idx = blockIdx.x*blockDim.x + threadIdx.x;    // over NN0*MM*DD
  if (idx >= NN0*MM*DD) return;
  int i = idx >> 8;            // node
  int md = idx & 255;
  int m = md >> 7, d = md & 127;
  float emb = thax_table[((size_t)m*NTHAX + thax_ids[i])*DD + d];
  float s = (float)sine_ids[i];
  float z = s*sine_w[m*DD + d] + sine_b[m*DD + d];
  float sig = 1.f/(1.f + expf(-z));
  store[idx] = emb*sig;
}

// ---------------------------------------------------------------------------
// Totals: per-block partial sums of pos/neg (no atomics)
// ---------------------------------------------------------------------------
__global__ void totals_kernel(const float* __restrict__ pos, const float* __restrict__ neg,
                              float* __restrict__ pt)
{
  __shared__ float ts[4][2];
  const int t = threadIdx.x, lane = t & 63;
  float sp = 0.f, sn = 0.f;
  for (int n = blockIdx.x*blockDim.x + t; n < NTOT; n += gridDim.x*blockDim.x){
    sp += pos[n]; sn += neg[n];
  }
  #pragma unroll
  for (int s = 1; s < 64; s <<= 1){ sp += __shfl_xor(sp, s, 64); sn += __shfl_xor(sn, s, 64); }
  if (lane == 0){ ts[t>>6][0] = sp; ts[t>>6][1] = sn; }
  __syncthreads();
  if (t < 2) pt[t*TBLK + blockIdx.x] = ts[0][t] + ts[1][t] + ts[2][t] + ts[3][t];
}

// ---------------------------------------------------------------------------
// One level via MFMA: block = (chunk of 16 same-rule nodes, member m).
// 4 waves; wave w owns e-slice [w*32, w*32+32).  Per wave per layer:
// K/32 steps x 2 (16x16x32 bf16) MFMA.  X gathered fp32 -> bf16 in LDS
// (XOR-swizzled, G4); weights read from pre-transposed bf16 B-frag layout.
// fp32 accumulate; outputs written fp32 to store.
// ---------------------------------------------------------------------------
__global__ __launch_bounds__(256, 2) void level_kernel(
    float* __restrict__ store,
    const int* __restrict__ parents,      // [LLV][KK][2]
    const int* __restrict__ chunk_nodes,  // [LLV][CHN16][NB]
    const int* __restrict__ chunk_rule,   // [LLV][CHN16]
    const int* __restrict__ nchunks,      // [LLV]
    const unsigned short* __restrict__ W1t, const float* __restrict__ b1,
    const unsigned short* __restrict__ W2t, const float* __restrict__ b2,
    int level)
{
  const int c = blockIdx.x;
  if (c >= nchunks[level]) return;
  const int m = blockIdx.y;
  const int r = chunk_rule[level*CHN16 + c];

  __shared__ __align__(16) unsigned short Xs[16*256];  // 8KB bf16, swizzled rows of 512B
  __shared__ __align__(16) unsigned short Hs[16*128];  // 4KB bf16, swizzled rows of 256B
  __shared__ int nd[NB];
  __shared__ int par[NB][2];

  const int t  = threadIdx.x;
  const int w  = t >> 6;        // wave -> e-slice
  const int l  = t & 63;
  const int lr = l & 15;        // row (A) / col (B,D) within tile
  const int lg = l >> 4;        // k-group (A,B) / row-group (D)

  if (t < NB){
    int node = chunk_nodes[(level*CHN16 + c)*NB + t];
    nd[t] = node;
    const int* parL = parents + (size_t)level*KK*2;
    int p0 = 0, p1 = 0;
    if (node >= 0){ p0 = parL[node*2]; p1 = parL[node*2 + 1]; }
    par[t][0] = p0; par[t][1] = p1;
  }
  __syncthreads();

  // ---- Stage X: 1024 float4 gathers (4/thread, 512B coalesced runs),
  //      convert to bf16, swizzled LDS write ----
  #pragma unroll
  for (int q4 = 0; q4 < 4; ++q4){
    int q = q4*256 + t;                 // 0..1023
    int n = q >> 6, dq = q & 63;        // dq = float4 index within 256-float row
    int p = par[n][dq >> 5];
    int col = (dq & 31)*4;
    float4 v = *(const float4*)(store + (size_t)p*(MM*DD) + m*DD + col);
    ushort4 b;
    b.x = f2bf(v.x); b.y = f2bf(v.y); b.z = f2bf(v.z); b.w = f2bf(v.w);
    int addr = n*512 + ((dq*8) ^ ((n & 7) << 4));
    *(ushort4*)((char*)Xs + addr) = b;
  }
  __syncthreads();

  // ---------------- Layer 1: C[16x32slice] = X[16x256] * W1 ----------------
  const unsigned short* W1p = W1t + (size_t)(m*RR + r)*(256/8)*DD*8;
  f32x4 acc0 = {0.f,0.f,0.f,0.f}, acc1 = {0.f,0.f,0.f,0.f};
  #pragma unroll
  for (int s = 0; s < 8; ++s){          // k = s*32
    int ab = lr*512 + ((s*64 + lg*16) ^ ((lr & 7) << 4));
    bf16x8 a = *(const bf16x8*)((const char*)Xs + ab);
    const unsigned short* bp = W1p + ((size_t)(s*4 + lg)*DD + w*32 + lr)*8;
    bf16x8 bf0 = *(const bf16x8*)bp;
    bf16x8 bf1 = *(const bf16x8*)(bp + 16*8);
    acc0 = __builtin_amdgcn_mfma_f32_16x16x32_bf16(a, bf0, acc0, 0, 0, 0);
    acc1 = __builtin_amdgcn_mfma_f32_16x16x32_bf16(a, bf1, acc1, 0, 0, 0);
  }

  // bias + relu -> Hs (bf16, swizzled).  D: col=lr(+e-slice), row=lg*4+reg.
  {
    const float* b1v = b1 + (m*RR + r)*DD;
    int col0 = w*32 + lr;
    float bb0 = b1v[col0], bb1 = b1v[col0 + 16];
    #pragma unroll
    for (int reg = 0; reg < 4; ++reg){
      int row = lg*4 + reg;
      float h0 = fmaxf(acc0[reg] + bb0, 0.f);
      float h1 = fmaxf(acc1[reg] + bb1, 0.f);
      int sw = (row & 7) << 4;
      *(unsigned short*)((char*)Hs + row*256 + ((col0*2) ^ sw))        = f2bf(h0);
      *(unsigned short*)((char*)Hs + row*256 + (((col0 + 16)*2) ^ sw)) = f2bf(h1);
    }
  }
  __syncthreads();

  // ---------------- Layer 2: C[16x32slice] = H[16x128] * W2 ----------------
  const unsigned short* W2p = W2t + (size_t)(m*RR + r)*(128/8)*DD*8;
  acc0 = (f32x4){0.f,0.f,0.f,0.f};
  acc1 = (f32x4){0.f,0.f,0.f,0.f};
  #pragma unroll
  for (int s = 0; s < 4; ++s){          // k = s*32
    int ab = lr*256 + ((s*64 + lg*16) ^ ((lr & 7) << 4));
    bf16x8 a = *(const bf16x8*)((const char*)Hs + ab);
    const unsigned short* bp = W2p + ((size_t)(s*4 + lg)*DD + w*32 + lr)*8;
    bf16x8 bf0 = *(const bf16x8*)bp;
    bf16x8 bf1 = *(const bf16x8*)(bp + 16*8);
    acc0 = __builtin_amdgcn_mfma_f32_16x16x32_bf16(a, bf0, acc0, 0, 0, 0);
    acc1 = __builtin_amdgcn_mfma_f32_16x16x32_bf16(a, bf1, acc1, 0, 0, 0);
  }

  // epilogue: + b2, write fp32 rows of store (64B runs per 16-lane group)
  {
    const float* b2v = b2 + (m*RR + r)*DD;
    const size_t obase = (size_t)NN0 + (size_t)level*KK;
    int col0 = w*32 + lr;
    float bb0 = b2v[col0], bb1 = b2v[col0 + 16];
    #pragma unroll
    for (int reg = 0; reg < 4; ++reg){
      int row = lg*4 + reg;
      int node = nd[row];
      if (node >= 0){
        float* op = store + (obase + node)*(MM*DD) + m*DD;
        op[col0]      = acc0[reg] + bb0;
        op[col0 + 16] = acc1[reg] + bb1;
      }
    }
  }
}

// ---------------------------------------------------------------------------
// Eval: wave-per-node dot with w_eval (both m in one wave), stable BCE.
// Per-block partials (NO atomics): pe[c][blk], c = q*2 + m,
// q: 0=A (pw part), 1=B, 2=posOK, 3=negOK.  loss = pw*A + B in finish.
// ---------------------------------------------------------------------------
__global__ void eval_kernel(const float* __restrict__ store,
                            const float* __restrict__ pos_cnt, const float* __restrict__ neg_cnt,
                            const float* __restrict__ w_eval, const float* __restrict__ b_eval,
                            float* __restrict__ pe)
{
  __shared__ float part[4][2][4];      // [wave][m][q]
  const int t = threadIdx.x, lane = t & 63;
  const int gw = blockIdx.x*(blockDim.x >> 6) + (t >> 6);
  const int nw = gridDim.x*(blockDim.x >> 6);
  float4 wv = *(const float4*)&w_eval[4*lane];          // lanes 0-31 -> m=0, 32-63 -> m=1
  const int m = (lane >= 32) ? 1 : 0;
  const float be = b_eval[m];
  float A = 0.f, B = 0.f, pOK = 0.f, nOK = 0.f;
  for (int n = gw; n < NTOT; n += nw){
    float4 v = *(const float4*)&store[(size_t)n*(MM*DD) + 4*lane];
    float p = v.x*wv.x + v.y*wv.y + v.z*wv.z + v.w*wv.w;
    #pragma unroll
    for (int s = 1; s < 32; s <<= 1) p += __shfl_xor(p, s, 64);   // reduce within each m-half
    const float val = p + be;
    if ((lane & 31) == 0){
      const float pc = pos_cnt[n], nc = neg_cnt[n];
      const float cnt = pc + nc;
      if (cnt > 0.f){
        float gold = pc / fmaxf(cnt, 1.f);
        float e = log1pf(expf(-fabsf(val)));
        float sp_pos = e + fmaxf(val, 0.f);     // softplus(val)
        float sp_neg = e + fmaxf(-val, 0.f);    // softplus(-val)
        A += cnt * gold * sp_neg;
        B += cnt * (1.f - gold) * sp_pos;
      }
      pOK += (val >= 0.f) ? pc : 0.f;
      nOK += (val <  0.f) ? nc : 0.f;
    }
  }
  if ((lane & 31) == 0){
    int wv2 = t >> 6;
    part[wv2][m][0] = A; part[wv2][m][1] = B; part[wv2][m][2] = pOK; part[wv2][m][3] = nOK;
  }
  __syncthreads();
  if (t < 8){
    int q = t >> 1, mm = t & 1;
    float s = part[0][mm][q] + part[1][mm][q] + part[2][mm][q] + part[3][mm][q];
    pe[t*EBLK + blockIdx.x] = s;
  }
}

// ---------------------------------------------------------------------------
// Finish: reduce totals + eval partials, compute pw, write 6 outputs.
// ---------------------------------------------------------------------------
__global__ void finish_kernel(const float* __restrict__ pt, const float* __restrict__ pe,
                              float* __restrict__ out)
{
  __shared__ float acc8[8];
  __shared__ float tt[2];
  const int t = threadIdx.x;             // 256
  if (t < 64){                           // totals: comp c = t>>5
    int c = t >> 5, l = t & 31;
    float s = pt[c*TBLK + l] + pt[c*TBLK + l + 32];
    #pragma unroll
    for (int d = 1; d < 32; d <<= 1) s += __shfl_xor(s, d, 64);
    if (l == 0) tt[c] = s;
  }
  {
    int comp = t >> 5, l = t & 31;
    float s = 0.f;
    for (int i = 0; i < EBLK/32; ++i) s += pe[comp*EBLK + i*32 + l];
    #pragma unroll
    for (int d = 1; d < 32; d <<= 1) s += __shfl_xor(s, d, 64);
    if (l == 0) acc8[comp] = s;
  }
  __syncthreads();
  if (t < 2){                            // m = t
    float tp = tt[0], tn = tt[1];
    float pw = (tp > 0.f) ? (tn / fmaxf(tp, 1.f)) : 1.f;   // POS_WEIGHT_EXTRA = 1
    out[t]     = pw*acc8[0 + t] + acc8[2 + t];
    out[2 + t] = acc8[4 + t];
    out[4 + t] = acc8[6 + t];
  }
}

// ---------------------------------------------------------------------------
extern "C" void kernel_launch(void* const* d_in, const int* in_sizes, int n_in,
                              void* d_out, int out_size, void* d_ws, size_t ws_size,
                              hipStream_t stream)
{
  const int*   thax_ids   = (const int*)d_in[0];
  const int*   sine_ids   = (const int*)d_in[1];
  const int*   parents    = (const int*)d_in[2];
  const int*   rule_ids   = (const int*)d_in[3];
  const float* pos_cnt    = (const float*)d_in[4];
  const float* neg_cnt    = (const float*)d_in[5];
  const float* thax_table = (const float*)d_in[6];
  const float* sine_w     = (const float*)d_in[7];
  const float* sine_b     = (const float*)d_in[8];
  const float* W1         = (const float*)d_in[9];
  const float* b1         = (const float*)d_in[10];
  const float* W2         = (const float*)d_in[11];
  const float* b2         = (const float*)d_in[12];
  const float* w_eval     = (const float*)d_in[13];
  const float* b_eval     = (const float*)d_in[14];

  char* ws = (char*)d_ws;
  float* store = (float*)ws;
  size_t off = (size_t)NTOT*MM*DD*sizeof(float);            // 142.6 MB
  int* chunk_nodes = (int*)(ws + off); off += (size_t)LLV*CHN16*NB*sizeof(int);
  int* chunk_rule  = (int*)(ws + off); off += (size_t)LLV*CHN16*sizeof(int);
  int* nchunks     = (int*)(ws + off); off += (size_t)LLV*sizeof(int);
  float* pt        = (float*)(ws + off); off += (size_t)2*TBLK*sizeof(float);
  float* pe        = (float*)(ws + off); off += (size_t)8*EBLK*sizeof(float);
  off = (off + 15) & ~(size_t)15;
  unsigned short* W1t = (unsigned short*)(ws + off); off += (size_t)MM*RR*256*DD*sizeof(unsigned short);
  unsigned short* W2t = (unsigned short*)(ws + off); off += (size_t)MM*RR*128*DD*sizeof(unsigned short);

  prep_kernel<<<LLV, 256, 0, stream>>>(rule_ids, chunk_nodes, chunk_rule, nchunks);
  convw_kernel<<<(MM*RR*256*DD + 255)/256, 256, 0, stream>>>(W1, W1t, 256);
  convw_kernel<<<(MM*RR*128*DD + 255)/256, 256, 0, stream>>>(W2, W2t, 128);
  init_kernel<<<(NN0*MM*DD + 255)/256, 256, 0, stream>>>(thax_ids, sine_ids, thax_table,
                                                         sine_w, sine_b, store);
  totals_kernel<<<TBLK, 256, 0, stream>>>(pos_cnt, neg_cnt, pt);

  for (int l = 0; l < LLV; ++l)
    level_kernel<<<dim3(CHN16, MM), 256, 0, stream>>>(store, parents, chunk_nodes, chunk_rule,
                                                      nchunks, W1t, b1, W2t, b2, l);

  eval_kernel<<<EBLK, 256, 0, stream>>>(store, pos_cnt, neg_cnt, w_eval, b_eval, pe);
  finish_kernel<<<1, 256, 0, stream>>>(pt, pe, (float*)d_out);
}

// Round 13
// 328.527 us; speedup vs baseline: 8.2645x; 1.0722x over previous
//
#include <hip/hip_runtime.h>
#include <cstdint>
#include <cstddef>

// Problem constants (match the JAX reference)
#define MM 2
#define DD 128
#define RR 8
#define NN0 8192
#define LLV 32
#define KK 4096
#define NTHAX 1000
#define NTOT (NN0 + LLV*KK)     // 139264
#define NB 16                   // nodes per chunk (MFMA M-tile)
#define CHN16 264               // max chunks/level: ceil((4096 + 8*15)/16) = 264
#define EBLK 2048               // eval blocks
#define TBLK 64                 // totals blocks

typedef short bf16x8 __attribute__((ext_vector_type(8)));   // 8 bf16 (4 VGPRs)
typedef float f32x4  __attribute__((ext_vector_type(4)));

__device__ __forceinline__ unsigned short f2bf(float f){
  union { float f; uint32_t u; } x; x.f = f;
  uint32_t u = x.u + 0x7FFFu + ((x.u >> 16) & 1u);   // RNE
  return (unsigned short)(u >> 16);
}
__device__ __forceinline__ float bf2f(unsigned short h){
  union { uint32_t u; float f; } x; x.u = ((uint32_t)h) << 16; return x.f;
}

// ---------------------------------------------------------------------------
// Preprocess: per level, counting-sort node indices by rule into NB-padded
// chunks so each level-kernel block handles exactly one rule.
// ---------------------------------------------------------------------------
__global__ void prep_kernel(const int* __restrict__ rule_ids,
                            int* __restrict__ chunk_nodes,   // [LLV][CHN16][NB]
                            int* __restrict__ chunk_rule,    // [LLV][CHN16]
                            int* __restrict__ nchunks)       // [LLV]
{
  const int l = blockIdx.x, t = threadIdx.x;
  __shared__ int cnt[RR], start[RR], fill[RR];
  if (t < RR){ cnt[t] = 0; fill[t] = 0; }
  __syncthreads();
  for (int k = t; k < KK; k += blockDim.x) atomicAdd(&cnt[rule_ids[l*KK + k]], 1);
  __syncthreads();
  if (t == 0){
    int s = 0;
    for (int r = 0; r < RR; ++r){
      start[r] = s;
      int pad = (cnt[r] + NB - 1)/NB*NB;
      for (int c = s/NB; c < (s+pad)/NB; ++c) chunk_rule[l*CHN16 + c] = r;
      s += pad;
    }
    nchunks[l] = s/NB;
  }
  __syncthreads();
  for (int i = t; i < CHN16*NB; i += blockDim.x) chunk_nodes[l*CHN16*NB + i] = -1;
  __syncthreads();
  for (int k = t; k < KK; k += blockDim.x){
    int r = rule_ids[l*KK + k];
    int p = start[r] + atomicAdd(&fill[r], 1);   // LDS atomics only
    chunk_nodes[l*CHN16*NB + p] = k;
  }
}

// ---------------------------------------------------------------------------
// Weight conversion fp32 -> bf16 in MFMA-B-fragment-native layout (both W1,W2):
// Wt[(mr*(K/8) + kb)*DD*8 + e*8 + j] = bf16(W[(mr*K + kb*8+j)*DD + e])
// ---------------------------------------------------------------------------
__global__ void convw_kernel(const float* __restrict__ W1, const float* __restrict__ W2,
                             unsigned short* __restrict__ W1t, unsigned short* __restrict__ W2t)
{
  int idx = blockIdx.x*blockDim.x + threadIdx.x;
  const int N1 = MM*RR*256*DD;
  const int N2 = MM*RR*128*DD;
  if (idx < N1){
    int e = idx & 127;
    int k = (idx >> 7) & 255;        // K=256
    int mr = idx >> 15;
    float v = W1[((size_t)mr*256 + k)*DD + e];
    W1t[((size_t)mr*32 + (k >> 3))*DD*8 + e*8 + (k & 7)] = f2bf(v);
  } else {
    idx -= N1;
    if (idx >= N2) return;
    int e = idx & 127;
    int k = (idx >> 7) & 127;        // K=128
    int mr = idx >> 14;
    float v = W2[((size_t)mr*128 + k)*DD + e];
    W2t[((size_t)mr*16 + (k >> 3))*DD*8 + e*8 + (k & 7)] = f2bf(v);
  }
}

// ---------------------------------------------------------------------------
// Init nodes (bf16 store): store[i][m][d] = bf16(emb * sigmoid(s*w + b))
// ---------------------------------------------------------------------------
__global__ void init_kernel(const int* __restrict__ thax_ids, const int* __restrict__ sine_ids,
                            const float* __restrict__ thax_table,
                            const float* __restrict__ sine_w, const float* __restrict__ sine_b,
                            unsigned short* __restrict__ store)
{
  int idx = blockIdx.x*blockDim.x + threadIdx.x;    // over NN0*MM*DD
  if (idx >= NN0*MM*DD) return;
  int i = idx >> 8;            // node
  int md = idx & 255;
  int m = md >> 7, d = md & 127;
  float emb = thax_table[((size_t)m*NTHAX + thax_ids[i])*DD + d];
  float s = (float)sine_ids[i];
  float z = s*sine_w[m*DD + d] + sine_b[m*DD + d];
  float sig = 1.f/(1.f + expf(-z));
  store[idx] = f2bf(emb*sig);
}

// ---------------------------------------------------------------------------
// Totals: per-block partial sums of pos/neg (no atomics)
// ---------------------------------------------------------------------------
__global__ void totals_kernel(const float* __restrict__ pos, const float* __restrict__ neg,
                              float* __restrict__ pt)
{
  __shared__ float ts[4][2];
  const int t = threadIdx.x, lane = t & 63;
  float sp = 0.f, sn = 0.f;
  for (int n = blockIdx.x*blockDim.x + t; n < NTOT; n += gridDim.x*blockDim.x){
    sp += pos[n]; sn += neg[n];
  }
  #pragma unroll
  for (int s = 1; s < 64; s <<= 1){ sp += __shfl_xor(sp, s, 64); sn += __shfl_xor(sn, s, 64); }
  if (lane == 0){ ts[t>>6][0] = sp; ts[t>>6][1] = sn; }
  __syncthreads();
  if (t < 2) pt[t*TBLK + blockIdx.x] = ts[0][t] + ts[1][t] + ts[2][t] + ts[3][t];
}

// ---------------------------------------------------------------------------
// One level via MFMA (bf16 store): block = (chunk of 16 same-rule nodes, m).
// XCD-pair swizzle: blocks bid and bid+8 handle (c,m=0)/(c,m=1) -> same XCD,
// so the second gather of a chunk's parent rows hits that XCD's L2.
// 4 waves; wave w owns e-slice [w*32, w*32+32).  fp32 accumulate.
// ---------------------------------------------------------------------------
__global__ __launch_bounds__(256, 4) void level_kernel(
    unsigned short* __restrict__ store,
    const int* __restrict__ parents,      // [LLV][KK][2]
    const int* __restrict__ chunk_nodes,  // [LLV][CHN16][NB]
    const int* __restrict__ chunk_rule,   // [LLV][CHN16]
    const int* __restrict__ nchunks,      // [LLV]
    const unsigned short* __restrict__ W1t, const float* __restrict__ b1,
    const unsigned short* __restrict__ W2t, const float* __restrict__ b2,
    int level)
{
  const int bid = blockIdx.x;
  const int c = (bid >> 4)*8 + (bid & 7);       // XCD-pair swizzle
  const int m = (bid >> 3) & 1;
  if (c >= nchunks[level]) return;
  const int r = chunk_rule[level*CHN16 + c];

  __shared__ __align__(16) unsigned short Xs[16*256];  // 8KB bf16, swizzled rows of 512B
  __shared__ __align__(16) unsigned short Hs[16*128];  // 4KB bf16, swizzled rows of 256B
  __shared__ int nd[NB];
  __shared__ int par[NB][2];

  const int t  = threadIdx.x;
  const int w  = t >> 6;        // wave -> e-slice
  const int l  = t & 63;
  const int lr = l & 15;        // row (A) / col (B,D) within tile
  const int lg = l >> 4;        // k-group (A,B) / row-group (D)

  if (t < NB){
    int node = chunk_nodes[(level*CHN16 + c)*NB + t];
    nd[t] = node;
    const int* parL = parents + (size_t)level*KK*2;
    int p0 = 0, p1 = 0;
    if (node >= 0){ p0 = parL[node*2]; p1 = parL[node*2 + 1]; }
    par[t][0] = p0; par[t][1] = p1;
  }
  __syncthreads();

  // ---- Stage X: 1024 ushort4 gathers (4/thread, 256B coalesced runs),
  //      swizzled LDS write (already bf16 in store) ----
  #pragma unroll
  for (int q4 = 0; q4 < 4; ++q4){
    int q = q4*256 + t;                 // 0..1023
    int n = q >> 6, dq = q & 63;        // dq = ushort4 index within 256-bf16 row
    int p = par[n][dq >> 5];
    int col = (dq & 31)*4;
    ushort4 v = *(const ushort4*)(store + (size_t)p*(MM*DD) + m*DD + col);
    int addr = n*512 + ((dq*8) ^ ((n & 7) << 4));
    *(ushort4*)((char*)Xs + addr) = v;
  }
  __syncthreads();

  // ---------------- Layer 1: C[16x32slice] = X[16x256] * W1 ----------------
  const unsigned short* W1p = W1t + (size_t)(m*RR + r)*(256/8)*DD*8;
  f32x4 acc0 = {0.f,0.f,0.f,0.f}, acc1 = {0.f,0.f,0.f,0.f};
  #pragma unroll
  for (int s = 0; s < 8; ++s){          // k = s*32
    int ab = lr*512 + ((s*64 + lg*16) ^ ((lr & 7) << 4));
    bf16x8 a = *(const bf16x8*)((const char*)Xs + ab);
    const unsigned short* bp = W1p + ((size_t)(s*4 + lg)*DD + w*32 + lr)*8;
    bf16x8 bf0 = *(const bf16x8*)bp;
    bf16x8 bf1 = *(const bf16x8*)(bp + 16*8);
    acc0 = __builtin_amdgcn_mfma_f32_16x16x32_bf16(a, bf0, acc0, 0, 0, 0);
    acc1 = __builtin_amdgcn_mfma_f32_16x16x32_bf16(a, bf1, acc1, 0, 0, 0);
  }

  // bias + relu -> Hs (bf16, swizzled).  D: col=lr(+e-slice), row=lg*4+reg.
  {
    const float* b1v = b1 + (m*RR + r)*DD;
    int col0 = w*32 + lr;
    float bb0 = b1v[col0], bb1 = b1v[col0 + 16];
    #pragma unroll
    for (int reg = 0; reg < 4; ++reg){
      int row = lg*4 + reg;
      float h0 = fmaxf(acc0[reg] + bb0, 0.f);
      float h1 = fmaxf(acc1[reg] + bb1, 0.f);
      int sw = (row & 7) << 4;
      *(unsigned short*)((char*)Hs + row*256 + ((col0*2) ^ sw))        = f2bf(h0);
      *(unsigned short*)((char*)Hs + row*256 + (((col0 + 16)*2) ^ sw)) = f2bf(h1);
    }
  }
  __syncthreads();

  // ---------------- Layer 2: C[16x32slice] = H[16x128] * W2 ----------------
  const unsigned short* W2p = W2t + (size_t)(m*RR + r)*(128/8)*DD*8;
  acc0 = (f32x4){0.f,0.f,0.f,0.f};
  acc1 = (f32x4){0.f,0.f,0.f,0.f};
  #pragma unroll
  for (int s = 0; s < 4; ++s){          // k = s*32
    int ab = lr*256 + ((s*64 + lg*16) ^ ((lr & 7) << 4));
    bf16x8 a = *(const bf16x8*)((const char*)Hs + ab);
    const unsigned short* bp = W2p + ((size_t)(s*4 + lg)*DD + w*32 + lr)*8;
    bf16x8 bf0 = *(const bf16x8*)bp;
    bf16x8 bf1 = *(const bf16x8*)(bp + 16*8);
    acc0 = __builtin_amdgcn_mfma_f32_16x16x32_bf16(a, bf0, acc0, 0, 0, 0);
    acc1 = __builtin_amdgcn_mfma_f32_16x16x32_bf16(a, bf1, acc1, 0, 0, 0);
  }

  // epilogue: + b2, write bf16 rows of store
  {
    const float* b2v = b2 + (m*RR + r)*DD;
    const size_t obase = (size_t)NN0 + (size_t)level*KK;
    int col0 = w*32 + lr;
    float bb0 = b2v[col0], bb1 = b2v[col0 + 16];
    #pragma unroll
    for (int reg = 0; reg < 4; ++reg){
      int row = lg*4 + reg;
      int node = nd[row];
      if (node >= 0){
        unsigned short* op = store + (obase + node)*(MM*DD) + m*DD;
        op[col0]      = f2bf(acc0[reg] + bb0);
        op[col0 + 16] = f2bf(acc1[reg] + bb1);
      }
    }
  }
}

// ---------------------------------------------------------------------------
// Eval (bf16 store): wave-per-node dot with w_eval, stable BCE.
// Per-block partials (NO atomics): pe[c][blk], c = q*2 + m,
// q: 0=A (pw part), 1=B, 2=posOK, 3=negOK.  loss = pw*A + B in finish.
// ---------------------------------------------------------------------------
__global__ void eval_kernel(const unsigned short* __restrict__ store,
                            const float* __restrict__ pos_cnt, const float* __restrict__ neg_cnt,
                            const float* __restrict__ w_eval, const float* __restrict__ b_eval,
                            float* __restrict__ pe)
{
  __shared__ float part[4][2][4];      // [wave][m][q]
  const int t = threadIdx.x, lane = t & 63;
  const int gw = blockIdx.x*(blockDim.x >> 6) + (t >> 6);
  const int nw = gridDim.x*(blockDim.x >> 6);
  float4 wv = *(const float4*)&w_eval[4*lane];          // lanes 0-31 -> m=0, 32-63 -> m=1
  const int m = (lane >= 32) ? 1 : 0;
  const float be = b_eval[m];
  float A = 0.f, B = 0.f, pOK = 0.f, nOK = 0.f;
  for (int n = gw; n < NTOT; n += nw){
    ushort4 v4 = *(const ushort4*)&store[(size_t)n*(MM*DD) + 4*lane];
    float p = bf2f(v4.x)*wv.x + bf2f(v4.y)*wv.y + bf2f(v4.z)*wv.z + bf2f(v4.w)*wv.w;
    #pragma unroll
    for (int s = 1; s < 32; s <<= 1) p += __shfl_xor(p, s, 64);   // reduce within each m-half
    const float val = p + be;
    if ((lane & 31) == 0){
      const float pc = pos_cnt[n], nc = neg_cnt[n];
      const float cnt = pc + nc;
      if (cnt > 0.f){
        float gold = pc / fmaxf(cnt, 1.f);
        float e = log1pf(expf(-fabsf(val)));
        float sp_pos = e + fmaxf(val, 0.f);     // softplus(val)
        float sp_neg = e + fmaxf(-val, 0.f);    // softplus(-val)
        A += cnt * gold * sp_neg;
        B += cnt * (1.f - gold) * sp_pos;
      }
      pOK += (val >= 0.f) ? pc : 0.f;
      nOK += (val <  0.f) ? nc : 0.f;
    }
  }
  if ((lane & 31) == 0){
    int wv2 = t >> 6;
    part[wv2][m][0] = A; part[wv2][m][1] = B; part[wv2][m][2] = pOK; part[wv2][m][3] = nOK;
  }
  __syncthreads();
  if (t < 8){
    int q = t >> 1, mm = t & 1;
    float s = part[0][mm][q] + part[1][mm][q] + part[2][mm][q] + part[3][mm][q];
    pe[t*EBLK + blockIdx.x] = s;
  }
}

// ---------------------------------------------------------------------------
// Finish: reduce totals + eval partials, compute pw, write 6 outputs.
// ---------------------------------------------------------------------------
__global__ void finish_kernel(const float* __restrict__ pt, const float* __restrict__ pe,
                              float* __restrict__ out)
{
  __shared__ float acc8[8];
  __shared__ float tt[2];
  const int t = threadIdx.x;             // 256
  if (t < 64){                           // totals: comp c = t>>5
    int c = t >> 5, l = t & 31;
    float s = pt[c*TBLK + l] + pt[c*TBLK + l + 32];
    #pragma unroll
    for (int d = 1; d < 32; d <<= 1) s += __shfl_xor(s, d, 64);
    if (l == 0) tt[c] = s;
  }
  {
    int comp = t >> 5, l = t & 31;
    float s = 0.f;
    for (int i = 0; i < EBLK/32; ++i) s += pe[comp*EBLK + i*32 + l];
    #pragma unroll
    for (int d = 1; d < 32; d <<= 1) s += __shfl_xor(s, d, 64);
    if (l == 0) acc8[comp] = s;
  }
  __syncthreads();
  if (t < 2){                            // m = t
    float tp = tt[0], tn = tt[1];
    float pw = (tp > 0.f) ? (tn / fmaxf(tp, 1.f)) : 1.f;   // POS_WEIGHT_EXTRA = 1
    out[t]     = pw*acc8[0 + t] + acc8[2 + t];
    out[2 + t] = acc8[4 + t];
    out[4 + t] = acc8[6 + t];
  }
}

// ---------------------------------------------------------------------------
extern "C" void kernel_launch(void* const* d_in, const int* in_sizes, int n_in,
                              void* d_out, int out_size, void* d_ws, size_t ws_size,
                              hipStream_t stream)
{
  const int*   thax_ids   = (const int*)d_in[0];
  const int*   sine_ids   = (const int*)d_in[1];
  const int*   parents    = (const int*)d_in[2];
  const int*   rule_ids   = (const int*)d_in[3];
  const float* pos_cnt    = (const float*)d_in[4];
  const float* neg_cnt    = (const float*)d_in[5];
  const float* thax_table = (const float*)d_in[6];
  const float* sine_w     = (const float*)d_in[7];
  const float* sine_b     = (const float*)d_in[8];
  const float* W1         = (const float*)d_in[9];
  const float* b1         = (const float*)d_in[10];
  const float* W2         = (const float*)d_in[11];
  const float* b2         = (const float*)d_in[12];
  const float* w_eval     = (const float*)d_in[13];
  const float* b_eval     = (const float*)d_in[14];

  char* ws = (char*)d_ws;
  unsigned short* store = (unsigned short*)ws;
  size_t off = (size_t)NTOT*MM*DD*sizeof(unsigned short);   // 71.3 MB
  off = (off + 15) & ~(size_t)15;
  int* chunk_nodes = (int*)(ws + off); off += (size_t)LLV*CHN16*NB*sizeof(int);
  int* chunk_rule  = (int*)(ws + off); off += (size_t)LLV*CHN16*sizeof(int);
  int* nchunks     = (int*)(ws + off); off += (size_t)LLV*sizeof(int);
  float* pt        = (float*)(ws + off); off += (size_t)2*TBLK*sizeof(float);
  float* pe        = (float*)(ws + off); off += (size_t)8*EBLK*sizeof(float);
  off = (off + 15) & ~(size_t)15;
  unsigned short* W1t = (unsigned short*)(ws + off); off += (size_t)MM*RR*256*DD*sizeof(unsigned short);
  unsigned short* W2t = (unsigned short*)(ws + off); off += (size_t)MM*RR*128*DD*sizeof(unsigned short);

  prep_kernel<<<LLV, 256, 0, stream>>>(rule_ids, chunk_nodes, chunk_rule, nchunks);
  convw_kernel<<<(MM*RR*(256+128)*DD + 255)/256, 256, 0, stream>>>(W1, W2, W1t, W2t);
  init_kernel<<<(NN0*MM*DD + 255)/256, 256, 0, stream>>>(thax_ids, sine_ids, thax_table,
                                                         sine_w, sine_b, store);
  totals_kernel<<<TBLK, 256, 0, stream>>>(pos_cnt, neg_cnt, pt);

  for (int l = 0; l < LLV; ++l)
    level_kernel<<<CHN16*2, 256, 0, stream>>>(store, parents, chunk_nodes, chunk_rule,
                                              nchunks, W1t, b1, W2t, b2, l);

  eval_kernel<<<EBLK, 256, 0, stream>>>(store, pos_cnt, neg_cnt, w_eval, b_eval, pe);
  finish_kernel<<<1, 256, 0, stream>>>(pt, pe, (float*)d_out);
}